// Round 1
// baseline (4852.214 us; speedup 1.0000x reference)
//
#include <hip/hip_runtime.h>
#include <math.h>

#define TB 16
#define TT 2048
#define TD 256
#define TN 128
#define BN 2048   // TB*TN
#define BT 32768  // TB*TT
#define KTOP 100
#define NBINS 2048
#define LISTCAP 512

// ---------------------------------------------------------------------------
// Kernel A1: normalize negative rows (target_feature as (BT, D)) and store
// TRANSPOSED as nT[d][c] so the main kernel's reads are coalesced.
// One block handles 32 rows via an LDS tile.
// ---------------------------------------------------------------------------
__global__ __launch_bounds__(256) void knorm_neg(const float* __restrict__ tgt,
                                                 float* __restrict__ nT) {
    __shared__ float tile[32][257];
    __shared__ float partial[32][8];
    __shared__ float inv[32];
    const int tid = threadIdx.x;
    const int c0 = blockIdx.x * 32;

    // load 32 rows x 256 floats (coalesced float4)
    for (int k = 0; k < 8; ++k) {
        int idx = k * 256 + tid;
        int row = idx >> 6;       // 0..31
        int col4 = idx & 63;      // 0..63
        float4 v = *reinterpret_cast<const float4*>(tgt + (size_t)(c0 + row) * TD + col4 * 4);
        tile[row][col4 * 4 + 0] = v.x;
        tile[row][col4 * 4 + 1] = v.y;
        tile[row][col4 * 4 + 2] = v.z;
        tile[row][col4 * 4 + 3] = v.w;
    }
    __syncthreads();
    {
        int row = tid >> 3, part = tid & 7;
        float s = 0.f;
        for (int j = 0; j < 32; ++j) { float x = tile[row][part * 32 + j]; s += x * x; }
        partial[row][part] = s;
    }
    __syncthreads();
    if (tid < 32) {
        float s = 0.f;
        for (int j = 0; j < 8; ++j) s += partial[tid][j];
        inv[tid] = 1.0f / sqrtf(s);
    }
    __syncthreads();
    // write transposed: for each d (0..255) write 32 consecutive columns
    for (int k = 0; k < 8; ++k) {
        int idx = k * 256 + tid;
        int col4 = idx & 7;       // 8 groups of 4 columns
        int d = idx >> 3;         // 0..255
        float4 o;
        o.x = tile[col4 * 4 + 0][d] * inv[col4 * 4 + 0];
        o.y = tile[col4 * 4 + 1][d] * inv[col4 * 4 + 1];
        o.z = tile[col4 * 4 + 2][d] * inv[col4 * 4 + 2];
        o.w = tile[col4 * 4 + 3][d] * inv[col4 * 4 + 3];
        *reinterpret_cast<float4*>(nT + (size_t)d * BT + c0 + col4 * 4) = o;
    }
}

// ---------------------------------------------------------------------------
// Kernel A2: per anchor row r = b*TN + n: gather anchor/positive, compute
// normalized anchor (into ws), numerator term acos(cos_pos)*10, phone label.
// One wave (64 threads) per row.
// ---------------------------------------------------------------------------
__global__ __launch_bounds__(64) void kanchor(const float* __restrict__ ctx,
                                              const float* __restrict__ tgt,
                                              const int* __restrict__ mask_index,
                                              const int* __restrict__ phone,
                                              float* __restrict__ ancN,
                                              float* __restrict__ acosP,
                                              int* __restrict__ phoneA) {
    const int r = blockIdx.x;       // 0..BN-1
    const int b = r >> 7;
    const int n = r & 127;
    const int t = mask_index[n];
    const int lane = threadIdx.x;
    const size_t base = ((size_t)b * TT + t) * TD;
    float4 a = *reinterpret_cast<const float4*>(ctx + base + lane * 4);
    float4 p = *reinterpret_cast<const float4*>(tgt + base + lane * 4);
    float sa = a.x * a.x + a.y * a.y + a.z * a.z + a.w * a.w;
    float sp = p.x * p.x + p.y * p.y + p.z * p.z + p.w * p.w;
    float dp = a.x * p.x + a.y * p.y + a.z * p.z + a.w * p.w;
    for (int off = 32; off > 0; off >>= 1) {
        sa += __shfl_down(sa, off, 64);
        sp += __shfl_down(sp, off, 64);
        dp += __shfl_down(dp, off, 64);
    }
    sa = __shfl(sa, 0, 64);
    sp = __shfl(sp, 0, 64);
    dp = __shfl(dp, 0, 64);
    float an = sqrtf(sa);
    float inva = 1.0f / an;
    if (lane == 0) {
        float cp = dp / (an * sqrtf(sp));
        cp = fminf(1.f, fmaxf(-1.f, cp));
        acosP[r] = acosf(cp) * 10.0f;   // acos(cos_pos)/TEMPERATURE
        phoneA[r] = phone[b * TT + t];
    }
    float4 o;
    o.x = a.x * inva; o.y = a.y * inva; o.z = a.z * inva; o.w = a.w * inva;
    *reinterpret_cast<float4*>(ancN + (size_t)r * TD + lane * 4) = o;
}

// ---------------------------------------------------------------------------
// Kernel B: one block per anchor row.
//   pass 1: cos for all 32768 columns -> LDS buffer (masked = 2.0 sentinel)
//           + 2048-bin histogram of unmasked cos over [-1, 1]
//   scan:   find bin b* where cumulative count crosses K' = min(100, unmasked)
//   pass 2: sum exp(acos(v)*10) for bins < b*; collect bin==b* values;
//           exact min-extraction of the remaining few from the boundary bin.
// ---------------------------------------------------------------------------
__global__ __launch_bounds__(256) void kmain(const float* __restrict__ nT,
                                             const float* __restrict__ ancN,
                                             const float* __restrict__ acosP,
                                             const int* __restrict__ phoneA,
                                             const int* __restrict__ phoneT,
                                             float* __restrict__ logits) {
    extern __shared__ char smemraw[];
    float* cosbuf = (float*)smemraw;            // BT floats
    float* anc    = cosbuf + BT;                // TD floats
    float* list   = anc + TD;                   // LISTCAP floats
    float* redf   = list + LISTCAP;             // 256 floats
    int*   redi   = (int*)(redf + 256);         // 256 ints
    unsigned* hist = (unsigned*)(redi + 256);   // NBINS
    __shared__ int s_bstar, s_cbelow, s_kp, s_lc;
    __shared__ float s_den;

    const int tid = threadIdx.x;
    const int r = blockIdx.x;

    anc[tid] = ancN[(size_t)r * TD + tid];
    for (int i = tid; i < NBINS; i += 256) hist[i] = 0u;
    if (tid == 0) s_lc = 0;
    __syncthreads();

    const int mp = phoneA[r];
    const float4* nT4 = reinterpret_cast<const float4*>(nT);

    // ---- pass 1: compute cos, store, histogram ----
    for (int k = 0; k < 32; ++k) {
        const int c4 = k * 256 + tid;           // float4 column group
        float4 acc = make_float4(0.f, 0.f, 0.f, 0.f);
        for (int d = 0; d < TD; d += 4) {
            float4 a4 = *reinterpret_cast<float4*>(anc + d);
            float4 x0 = nT4[(size_t)(d + 0) * (BT / 4) + c4];
            float4 x1 = nT4[(size_t)(d + 1) * (BT / 4) + c4];
            float4 x2 = nT4[(size_t)(d + 2) * (BT / 4) + c4];
            float4 x3 = nT4[(size_t)(d + 3) * (BT / 4) + c4];
            acc.x = fmaf(a4.x, x0.x, acc.x);
            acc.y = fmaf(a4.x, x0.y, acc.y);
            acc.z = fmaf(a4.x, x0.z, acc.z);
            acc.w = fmaf(a4.x, x0.w, acc.w);
            acc.x = fmaf(a4.y, x1.x, acc.x);
            acc.y = fmaf(a4.y, x1.y, acc.y);
            acc.z = fmaf(a4.y, x1.z, acc.z);
            acc.w = fmaf(a4.y, x1.w, acc.w);
            acc.x = fmaf(a4.z, x2.x, acc.x);
            acc.y = fmaf(a4.z, x2.y, acc.y);
            acc.z = fmaf(a4.z, x2.z, acc.z);
            acc.w = fmaf(a4.z, x2.w, acc.w);
            acc.x = fmaf(a4.w, x3.x, acc.x);
            acc.y = fmaf(a4.w, x3.y, acc.y);
            acc.z = fmaf(a4.w, x3.z, acc.z);
            acc.w = fmaf(a4.w, x3.w, acc.w);
        }
        int4 ph = *reinterpret_cast<const int4*>(phoneT + c4 * 4);
        float v[4] = {acc.x, acc.y, acc.z, acc.w};
        int pp[4] = {ph.x, ph.y, ph.z, ph.w};
        float st[4];
        #pragma unroll
        for (int j = 0; j < 4; ++j) {
            float vv = fminf(1.f, fmaxf(-1.f, v[j]));
            if (pp[j] == mp) {
                vv = 2.0f;   // masked sentinel
            } else {
                int bb = (int)((vv + 1.0f) * (NBINS / 2));
                bb = bb > NBINS - 1 ? NBINS - 1 : bb;
                atomicAdd(&hist[bb], 1u);
            }
            st[j] = vv;
        }
        float4 stv = make_float4(st[0], st[1], st[2], st[3]);
        *reinterpret_cast<float4*>(cosbuf + c4 * 4) = stv;
    }
    __syncthreads();

    // ---- scan: find crossing bin ----
    unsigned* redu = (unsigned*)redi;
    {
        unsigned cs = 0;
        for (int j = 0; j < 8; ++j) cs += hist[tid * 8 + j];
        redu[tid] = cs;
    }
    __syncthreads();
    if (tid == 0) {
        unsigned tot = 0;
        for (int i = 0; i < 256; ++i) tot += redu[i];
        int kp = (int)tot < KTOP ? (int)tot : KTOP;
        unsigned cum = 0;
        int chunk = 0;
        for (; chunk < 256; ++chunk) {
            if (cum + redu[chunk] >= (unsigned)kp) break;
            cum += redu[chunk];
        }
        if (chunk > 255) chunk = 255;
        int bstar = NBINS - 1;
        for (int bb = chunk * 8; bb < chunk * 8 + 8; ++bb) {
            if (cum + hist[bb] >= (unsigned)kp) { bstar = bb; break; }
            cum += hist[bb];
        }
        s_bstar = bstar;
        s_cbelow = (int)cum;
        s_kp = kp;
    }
    __syncthreads();

    // ---- pass 2: sum below b*, collect boundary bin ----
    const int bstar = s_bstar;
    float lsum = 0.f;
    for (int k = 0; k < 32; ++k) {
        float4 v4 = *reinterpret_cast<float4*>(cosbuf + (k * 256 + tid) * 4);
        float v[4] = {v4.x, v4.y, v4.z, v4.w};
        #pragma unroll
        for (int j = 0; j < 4; ++j) {
            float vv = v[j];
            if (vv < 1.5f) {
                int bb = (int)((vv + 1.0f) * (NBINS / 2));
                bb = bb > NBINS - 1 ? NBINS - 1 : bb;
                if (bb < bstar) {
                    lsum += expf(acosf(vv) * 10.0f);
                } else if (bb == bstar) {
                    int i = atomicAdd(&s_lc, 1);
                    if (i < LISTCAP) list[i] = vv;
                }
            }
        }
    }
    redf[tid] = lsum;
    __syncthreads();
    for (int s = 128; s > 0; s >>= 1) {
        if (tid < s) redf[tid] += redf[tid + s];
        __syncthreads();
    }
    if (tid == 0) s_den = redf[0];
    __syncthreads();

    // ---- exact extraction of the remaining r smallest from boundary bin ----
    const int rneed = s_kp - s_cbelow;
    const int lc = s_lc < LISTCAP ? s_lc : LISTCAP;
    for (int it = 0; it < rneed; ++it) {
        float mv = 1e30f;
        int mi = -1;
        for (int i = tid; i < lc; i += 256) {
            if (list[i] < mv) { mv = list[i]; mi = i; }
        }
        redf[tid] = mv;
        redi[tid] = mi;
        __syncthreads();
        for (int s = 128; s > 0; s >>= 1) {
            if (tid < s && redf[tid + s] < redf[tid]) {
                redf[tid] = redf[tid + s];
                redi[tid] = redi[tid + s];
            }
            __syncthreads();
        }
        if (tid == 0) {
            float vv = redf[0];
            s_den += expf(acosf(fminf(1.f, fmaxf(-1.f, vv))) * 10.0f);
            if (redi[0] >= 0) list[redi[0]] = 1e30f;
        }
        __syncthreads();
    }

    if (tid == 0) logits[r] = acosP[r] - logf(s_den);
}

// ---------------------------------------------------------------------------
// Kernel C: deterministic final reduction. loss = -sum(logits)/ (N*B)
// ---------------------------------------------------------------------------
__global__ __launch_bounds__(256) void kloss(const float* __restrict__ logits,
                                             float* __restrict__ out) {
    __shared__ float red[256];
    int tid = threadIdx.x;
    float s = 0.f;
    for (int i = tid; i < BN; i += 256) s += logits[i];
    red[tid] = s;
    __syncthreads();
    for (int st = 128; st > 0; st >>= 1) {
        if (tid < st) red[tid] += red[tid + st];
        __syncthreads();
    }
    if (tid == 0) out[0] = -red[0] / (float)BN;
}

extern "C" void kernel_launch(void* const* d_in, const int* in_sizes, int n_in,
                              void* d_out, int out_size, void* d_ws, size_t ws_size,
                              hipStream_t stream) {
    (void)in_sizes; (void)n_in; (void)out_size; (void)ws_size;
    const float* ctx   = (const float*)d_in[0];
    const float* tgt   = (const float*)d_in[1];
    const int*   mask  = (const int*)d_in[2];
    const int*   phone = (const int*)d_in[3];
    float* out = (float*)d_out;

    float* nT     = (float*)d_ws;                 // BT*TD floats (32 MB)
    float* ancN   = nT + (size_t)BT * TD;         // BN*TD floats (2 MB)
    float* acosP  = ancN + (size_t)BN * TD;       // BN floats
    int*   phoneA = (int*)(acosP + BN);           // BN ints
    float* logits = (float*)(phoneA + BN);        // BN floats

    knorm_neg<<<BT / 32, 256, 0, stream>>>(tgt, nT);
    kanchor<<<BN, 64, 0, stream>>>(ctx, tgt, mask, phone, ancN, acosP, phoneA);
    size_t lds = (size_t)(BT + TD + LISTCAP + 256 + 256 + NBINS) * 4;  // 144384 B
    kmain<<<BN, 256, lds, stream>>>(nT, ancN, acosP, phoneA, phone, logits);
    kloss<<<1, 256, 0, stream>>>(logits, out);
}

// Round 2
// 419.140 us; speedup vs baseline: 11.5766x; 11.5766x over previous
//
#include <hip/hip_runtime.h>
#include <math.h>

#define TT 2048
#define TD 256
#define BN 2048
#define BT 32768
#define KTOP 100
#define NB 256      // histogram bins over [-1,1]
#define CAP 512     // per-row boundary-bin list capacity
#define RT 32       // anchor rows per block
#define CTN 8       // column tiles
#define CTILE 4096  // BT / CTN
#define NCHUNK 16   // CTILE / 256

typedef __attribute__((ext_vector_type(8))) short short8v;
typedef __attribute__((ext_vector_type(4))) float float4v;

__device__ __forceinline__ unsigned short f2bf(float f) {
    unsigned u = __float_as_uint(f);
    u += 0x7fffu + ((u >> 16) & 1u);   // round-to-nearest-even
    return (unsigned short)(u >> 16);
}

// ---------------------------------------------------------------------------
// zero global histogram + boundary-list counts (fresh every call)
// ---------------------------------------------------------------------------
__global__ __launch_bounds__(256) void kzero(unsigned* __restrict__ hist,
                                             int* __restrict__ cnt) {
    int i = blockIdx.x * 256 + threadIdx.x;   // grid covers BN*NB exactly
    hist[i] = 0u;
    if (i < BN) cnt[i] = 0;
}

// ---------------------------------------------------------------------------
// normalize negatives -> bf16 [BT][TD] row-major. one wave per row.
// ---------------------------------------------------------------------------
__global__ __launch_bounds__(256) void kprep(const float* __restrict__ tgt,
                                             unsigned short* __restrict__ negB) {
    const int row = blockIdx.x * 4 + (threadIdx.x >> 6);
    const int lane = threadIdx.x & 63;
    float4 v = *reinterpret_cast<const float4*>(tgt + (size_t)row * TD + lane * 4);
    float s = v.x * v.x + v.y * v.y + v.z * v.z + v.w * v.w;
    for (int off = 32; off > 0; off >>= 1) s += __shfl_down(s, off, 64);
    s = __shfl(s, 0, 64);
    const float inv = 1.0f / sqrtf(s);
    ushort4 o;
    o.x = f2bf(v.x * inv); o.y = f2bf(v.y * inv);
    o.z = f2bf(v.z * inv); o.w = f2bf(v.w * inv);
    *reinterpret_cast<ushort4*>(negB + (size_t)row * TD + lane * 4) = o;
}

// ---------------------------------------------------------------------------
// per anchor row: normalized anchor (bf16), numerator acos*10 (fp32), phone.
// ---------------------------------------------------------------------------
__global__ __launch_bounds__(64) void kanchor(const float* __restrict__ ctx,
                                              const float* __restrict__ tgt,
                                              const int* __restrict__ mask_index,
                                              const int* __restrict__ phone,
                                              unsigned short* __restrict__ ancB,
                                              float* __restrict__ acosP,
                                              int* __restrict__ phoneA) {
    const int r = blockIdx.x;
    const int b = r >> 7;
    const int n = r & 127;
    const int t = mask_index[n];
    const int lane = threadIdx.x;
    const size_t base = ((size_t)b * TT + t) * TD;
    float4 a = *reinterpret_cast<const float4*>(ctx + base + lane * 4);
    float4 p = *reinterpret_cast<const float4*>(tgt + base + lane * 4);
    float sa = a.x * a.x + a.y * a.y + a.z * a.z + a.w * a.w;
    float sp = p.x * p.x + p.y * p.y + p.z * p.z + p.w * p.w;
    float dp = a.x * p.x + a.y * p.y + a.z * p.z + a.w * p.w;
    for (int off = 32; off > 0; off >>= 1) {
        sa += __shfl_down(sa, off, 64);
        sp += __shfl_down(sp, off, 64);
        dp += __shfl_down(dp, off, 64);
    }
    sa = __shfl(sa, 0, 64);
    sp = __shfl(sp, 0, 64);
    dp = __shfl(dp, 0, 64);
    const float an = sqrtf(sa);
    const float inva = 1.0f / an;
    if (lane == 0) {
        float cp = dp / (an * sqrtf(sp));
        cp = fminf(1.f, fmaxf(-1.f, cp));
        acosP[r] = acosf(cp) * 10.0f;
        phoneA[r] = phone[b * TT + t];
    }
    ushort4 o;
    o.x = f2bf(a.x * inva); o.y = f2bf(a.y * inva);
    o.z = f2bf(a.z * inva); o.w = f2bf(a.w * inva);
    *reinterpret_cast<ushort4*>(ancB + (size_t)r * TD + lane * 4) = o;
}

// ---------------------------------------------------------------------------
// pass 1: MFMA cos tiles (32 rows x 4096 cols per block), per-row histogram
// in LDS, flush to global hist with integer atomics.
// ---------------------------------------------------------------------------
__global__ __launch_bounds__(256, 2) void kpass1(const unsigned short* __restrict__ negB,
                                                 const unsigned short* __restrict__ ancB,
                                                 const int* __restrict__ phoneT,
                                                 const int* __restrict__ phoneA,
                                                 unsigned* __restrict__ hist) {
    __shared__ unsigned short a_lds[RT][264];   // 16B-aligned rows, low-conflict
    __shared__ unsigned histl[RT][NB + 1];
    __shared__ int phA[RT];
    const int tid = threadIdx.x;
    const int w = tid >> 6;
    const int lane = tid & 63;
    const int g = lane >> 4;
    const int c = lane & 15;
    const int rt = blockIdx.x >> 3;
    const int ct = blockIdx.x & 7;
    const int row0 = rt * RT;
    const int col0 = ct * CTILE;

    for (int i = tid; i < RT * (NB + 1); i += 256) (&histl[0][0])[i] = 0u;
    for (int seg = tid; seg < RT * 32; seg += 256) {
        int r = seg >> 5, s = seg & 31;
        *reinterpret_cast<float4*>(&a_lds[r][s * 8]) =
            *reinterpret_cast<const float4*>(ancB + (size_t)(row0 + r) * TD + s * 8);
    }
    if (tid < RT) phA[tid] = phoneA[row0 + tid];
    __syncthreads();

    short8v af[2][8];
#pragma unroll
    for (int mt = 0; mt < 2; ++mt)
#pragma unroll
        for (int ks = 0; ks < 8; ++ks)
            af[mt][ks] = *reinterpret_cast<const short8v*>(&a_lds[mt * 16 + c][ks * 32 + g * 8]);

    for (int chunk = 0; chunk < NCHUNK; ++chunk) {
        const int cb = col0 + chunk * 256 + w * 64;
        float4v acc[2][4];
#pragma unroll
        for (int mt = 0; mt < 2; ++mt)
#pragma unroll
            for (int nt = 0; nt < 4; ++nt) {
                acc[mt][nt][0] = 0.f; acc[mt][nt][1] = 0.f;
                acc[mt][nt][2] = 0.f; acc[mt][nt][3] = 0.f;
            }
#pragma unroll
        for (int nt = 0; nt < 4; ++nt) {
            const size_t colbase = (size_t)(cb + nt * 16 + c) * TD;
#pragma unroll
            for (int ks = 0; ks < 8; ++ks) {
                short8v bf = *reinterpret_cast<const short8v*>(negB + colbase + ks * 32 + g * 8);
                acc[0][nt] = __builtin_amdgcn_mfma_f32_16x16x32_bf16(af[0][ks], bf, acc[0][nt], 0, 0, 0);
                acc[1][nt] = __builtin_amdgcn_mfma_f32_16x16x32_bf16(af[1][ks], bf, acc[1][nt], 0, 0, 0);
            }
        }
#pragma unroll
        for (int nt = 0; nt < 4; ++nt) {
            const int colg = cb + nt * 16 + c;
            const int ph = phoneT[colg];
#pragma unroll
            for (int mt = 0; mt < 2; ++mt) {
#pragma unroll
                for (int j = 0; j < 4; ++j) {
                    const int rl = mt * 16 + g * 4 + j;
                    if (ph != phA[rl]) {
                        float v = fminf(1.f, fmaxf(-1.f, acc[mt][nt][j]));
                        int bb = (int)((v + 1.0f) * 128.0f);
                        if (bb > NB - 1) bb = NB - 1;
                        atomicAdd(&histl[rl][bb], 1u);
                    }
                }
            }
        }
    }
    __syncthreads();
    for (int i = tid; i < RT * NB; i += 256) {
        int r = i >> 8, bb = i & 255;
        unsigned v = histl[r][bb];
        if (v) atomicAdd(&hist[(size_t)(row0 + r) * NB + bb], v);
    }
}

// ---------------------------------------------------------------------------
// find the k-th-value bin per row
// ---------------------------------------------------------------------------
__global__ __launch_bounds__(256) void kbstar(const unsigned* __restrict__ hist,
                                              int* __restrict__ bstar,
                                              int* __restrict__ rneedA) {
    const int row = blockIdx.x * 256 + threadIdx.x;
    const unsigned* h = hist + (size_t)row * NB;
    unsigned tot = 0;
    for (int i = 0; i < NB; ++i) tot += h[i];
    int kp = (int)tot < KTOP ? (int)tot : KTOP;
    if (kp == 0) { bstar[row] = -1; rneedA[row] = 0; return; }
    unsigned cum = 0;
    int b = 0;
    for (; b < NB; ++b) {
        if (cum + h[b] >= (unsigned)kp) break;
        cum += h[b];
    }
    bstar[row] = b;
    rneedA[row] = kp - (int)cum;
}

// ---------------------------------------------------------------------------
// pass 2: recompute cos (bit-identical), sum exp(acos*10) for bins < bstar
// (deterministic order), append boundary-bin values to per-row global lists.
// ---------------------------------------------------------------------------
__global__ __launch_bounds__(256, 2) void kpass2(const unsigned short* __restrict__ negB,
                                                 const unsigned short* __restrict__ ancB,
                                                 const int* __restrict__ phoneT,
                                                 const int* __restrict__ phoneA,
                                                 const int* __restrict__ bstar,
                                                 float* __restrict__ partials,
                                                 float* __restrict__ list,
                                                 int* __restrict__ cnt) {
    __shared__ unsigned short a_lds[RT][264];
    __shared__ int phA[RT];
    __shared__ int bsl[RT];
    __shared__ float rowpart[RT][4];
    const int tid = threadIdx.x;
    const int w = tid >> 6;
    const int lane = tid & 63;
    const int g = lane >> 4;
    const int c = lane & 15;
    const int rt = blockIdx.x >> 3;
    const int ct = blockIdx.x & 7;
    const int row0 = rt * RT;
    const int col0 = ct * CTILE;

    for (int seg = tid; seg < RT * 32; seg += 256) {
        int r = seg >> 5, s = seg & 31;
        *reinterpret_cast<float4*>(&a_lds[r][s * 8]) =
            *reinterpret_cast<const float4*>(ancB + (size_t)(row0 + r) * TD + s * 8);
    }
    if (tid < RT) {
        phA[tid] = phoneA[row0 + tid];
        bsl[tid] = bstar[row0 + tid];
    }
    __syncthreads();

    short8v af[2][8];
#pragma unroll
    for (int mt = 0; mt < 2; ++mt)
#pragma unroll
        for (int ks = 0; ks < 8; ++ks)
            af[mt][ks] = *reinterpret_cast<const short8v*>(&a_lds[mt * 16 + c][ks * 32 + g * 8]);

    float lsum[2][4];
#pragma unroll
    for (int mt = 0; mt < 2; ++mt)
#pragma unroll
        for (int j = 0; j < 4; ++j) lsum[mt][j] = 0.f;

    for (int chunk = 0; chunk < NCHUNK; ++chunk) {
        const int cb = col0 + chunk * 256 + w * 64;
        float4v acc[2][4];
#pragma unroll
        for (int mt = 0; mt < 2; ++mt)
#pragma unroll
            for (int nt = 0; nt < 4; ++nt) {
                acc[mt][nt][0] = 0.f; acc[mt][nt][1] = 0.f;
                acc[mt][nt][2] = 0.f; acc[mt][nt][3] = 0.f;
            }
#pragma unroll
        for (int nt = 0; nt < 4; ++nt) {
            const size_t colbase = (size_t)(cb + nt * 16 + c) * TD;
#pragma unroll
            for (int ks = 0; ks < 8; ++ks) {
                short8v bf = *reinterpret_cast<const short8v*>(negB + colbase + ks * 32 + g * 8);
                acc[0][nt] = __builtin_amdgcn_mfma_f32_16x16x32_bf16(af[0][ks], bf, acc[0][nt], 0, 0, 0);
                acc[1][nt] = __builtin_amdgcn_mfma_f32_16x16x32_bf16(af[1][ks], bf, acc[1][nt], 0, 0, 0);
            }
        }
#pragma unroll
        for (int nt = 0; nt < 4; ++nt) {
            const int colg = cb + nt * 16 + c;
            const int ph = phoneT[colg];
#pragma unroll
            for (int mt = 0; mt < 2; ++mt) {
#pragma unroll
                for (int j = 0; j < 4; ++j) {
                    const int rl = mt * 16 + g * 4 + j;
                    if (ph != phA[rl]) {
                        float v = fminf(1.f, fmaxf(-1.f, acc[mt][nt][j]));
                        int bb = (int)((v + 1.0f) * 128.0f);
                        if (bb > NB - 1) bb = NB - 1;
                        const int bs = bsl[rl];
                        if (bb < bs) {
                            lsum[mt][j] += expf(acosf(v) * 10.0f);
                        } else if (bb == bs) {
                            int idx = atomicAdd(&cnt[row0 + rl], 1);
                            if (idx < CAP) list[(size_t)(row0 + rl) * CAP + idx] = v;
                        }
                    }
                }
            }
        }
    }
    // deterministic per-row reduction: shuffle across the 16 lanes sharing a row
#pragma unroll
    for (int mt = 0; mt < 2; ++mt) {
#pragma unroll
        for (int j = 0; j < 4; ++j) {
            float s = lsum[mt][j];
            s += __shfl_xor(s, 1, 64);
            s += __shfl_xor(s, 2, 64);
            s += __shfl_xor(s, 4, 64);
            s += __shfl_xor(s, 8, 64);
            if (c == 0) rowpart[mt * 16 + g * 4 + j][w] = s;
        }
    }
    __syncthreads();
    if (tid < RT) {
        float s = ((rowpart[tid][0] + rowpart[tid][1]) + rowpart[tid][2]) + rowpart[tid][3];
        partials[(size_t)(row0 + tid) * CTN + ct] = s;
    }
}

// ---------------------------------------------------------------------------
// final per-row: sum partials (fixed order) + extract exact remainder from
// the boundary-bin list (ascending order -> deterministic). one wave per row.
// ---------------------------------------------------------------------------
__global__ __launch_bounds__(64) void kfinal(const float* __restrict__ partials,
                                             const float* __restrict__ list,
                                             const int* __restrict__ cnt,
                                             const int* __restrict__ rneedA,
                                             const float* __restrict__ acosP,
                                             float* __restrict__ logits) {
    __shared__ float sl[CAP];
    const int row = blockIdx.x;
    const int lane = threadIdx.x;
    int lc = cnt[row];
    if (lc > CAP) lc = CAP;
    int rn = rneedA[row];
    if (rn > lc) rn = lc;

    float den = 0.f;
    for (int t = 0; t < CTN; ++t) den += partials[(size_t)row * CTN + t];

    for (int i = lane; i < lc; i += 64) sl[i] = list[(size_t)row * CAP + i];
    __syncthreads();

    for (int it = 0; it < rn; ++it) {
        float mv = 1e30f;
        int mi = -1;
        for (int i = lane; i < lc; i += 64) {
            float x = sl[i];
            if (x < mv) { mv = x; mi = i; }
        }
#pragma unroll
        for (int off = 1; off < 64; off <<= 1) {
            float ov = __shfl_xor(mv, off, 64);
            int oi = __shfl_xor(mi, off, 64);
            if (ov < mv || (ov == mv && oi >= 0 && (mi < 0 || oi < mi))) { mv = ov; mi = oi; }
        }
        den += expf(acosf(mv) * 10.0f);
        if (lane == 0 && mi >= 0) sl[mi] = 1e30f;
        __syncthreads();
    }
    if (lane == 0) logits[row] = acosP[row] - logf(den);
}

__global__ __launch_bounds__(256) void kloss(const float* __restrict__ logits,
                                             float* __restrict__ out) {
    __shared__ float red[256];
    int tid = threadIdx.x;
    float s = 0.f;
    for (int i = tid; i < BN; i += 256) s += logits[i];
    red[tid] = s;
    __syncthreads();
    for (int st = 128; st > 0; st >>= 1) {
        if (tid < st) red[tid] += red[tid + st];
        __syncthreads();
    }
    if (tid == 0) out[0] = -red[0] / (float)BN;
}

extern "C" void kernel_launch(void* const* d_in, const int* in_sizes, int n_in,
                              void* d_out, int out_size, void* d_ws, size_t ws_size,
                              hipStream_t stream) {
    (void)in_sizes; (void)n_in; (void)out_size; (void)ws_size;
    const float* ctx   = (const float*)d_in[0];
    const float* tgt   = (const float*)d_in[1];
    const int*   mask  = (const int*)d_in[2];
    const int*   phone = (const int*)d_in[3];
    float* out = (float*)d_out;

    char* p = (char*)d_ws;
    unsigned short* negB = (unsigned short*)p;            p += (size_t)BT * TD * 2;  // 16 MB
    unsigned short* ancB = (unsigned short*)p;            p += (size_t)BN * TD * 2;  // 1 MB
    float* acosP  = (float*)p;                            p += (size_t)BN * 4;
    int*   phoneA = (int*)p;                              p += (size_t)BN * 4;
    unsigned* hist = (unsigned*)p;                        p += (size_t)BN * NB * 4;  // 2 MB
    int*   bstarA = (int*)p;                              p += (size_t)BN * 4;
    int*   rneedA = (int*)p;                              p += (size_t)BN * 4;
    int*   cntA   = (int*)p;                              p += (size_t)BN * 4;
    float* partials = (float*)p;                          p += (size_t)BN * CTN * 4;
    float* listA  = (float*)p;                            p += (size_t)BN * CAP * 4; // 4 MB
    float* logits = (float*)p;                            p += (size_t)BN * 4;

    kzero<<<(BN * NB) / 256, 256, 0, stream>>>(hist, cntA);
    kprep<<<BT / 4, 256, 0, stream>>>(tgt, negB);
    kanchor<<<BN, 64, 0, stream>>>(ctx, tgt, mask, phone, ancB, acosP, phoneA);
    kpass1<<<64 * CTN, 256, 0, stream>>>(negB, ancB, phone, phoneA, hist);
    kbstar<<<BN / 256, 256, 0, stream>>>(hist, bstarA, rneedA);
    kpass2<<<64 * CTN, 256, 0, stream>>>(negB, ancB, phone, phoneA, bstarA, partials, listA, cntA);
    kfinal<<<BN, 64, 0, stream>>>(partials, listA, cntA, rneedA, acosP, logits);
    kloss<<<1, 256, 0, stream>>>(logits, out);
}

// Round 3
// 334.816 us; speedup vs baseline: 14.4922x; 1.2519x over previous
//
#include <hip/hip_runtime.h>
#include <math.h>

#define TT 2048
#define TD 256
#define BN 2048
#define BT 32768
#define KTOP 100
#define NB 256      // histogram bins over [-1,1]
#define CAP 512     // per-row boundary-bin list capacity
#define RT 32       // anchor rows per block
#define CTN 16      // column tiles
#define CTILE 2048  // BT / CTN
#define WCOLS 512   // cols per wave
#define NCHUNK 8    // WCOLS / 64

typedef __attribute__((ext_vector_type(8))) short short8v;
typedef __attribute__((ext_vector_type(4))) float float4v;

__device__ __forceinline__ unsigned short f2bf(float f) {
    unsigned u = __float_as_uint(f);
    u += 0x7fffu + ((u >> 16) & 1u);   // round-to-nearest-even
    return (unsigned short)(u >> 16);
}

// ushort offset of (row_or_col, d0 = 4*lane) in the MFMA-fragment-tiled layout
// [blk16][ks(8)][g(4)][c(16)][8 elems]
__device__ __forceinline__ int tile_off_us(int col, int l) {
    int ks = l >> 3;
    int g = (l >> 1) & 3;
    int e = (l & 1) * 4;
    return ((((col >> 4) * 8 + ks) * 4 + g) * 16 + (col & 15)) * 8 + e;
}

// ---------------------------------------------------------------------------
// zero global histogram + boundary-list counts
// ---------------------------------------------------------------------------
__global__ __launch_bounds__(256) void kzero(unsigned* __restrict__ hist,
                                             int* __restrict__ cnt) {
    int i = blockIdx.x * 256 + threadIdx.x;   // grid covers BN*NB exactly
    hist[i] = 0u;
    if (i < BN) cnt[i] = 0;
}

// ---------------------------------------------------------------------------
// normalize negatives -> bf16, store in fragment-tiled layout. 1 wave per col.
// ---------------------------------------------------------------------------
__global__ __launch_bounds__(256) void kprep(const float* __restrict__ tgt,
                                             unsigned short* __restrict__ negT) {
    const int col = blockIdx.x * 4 + (threadIdx.x >> 6);
    const int lane = threadIdx.x & 63;
    float4 v = *reinterpret_cast<const float4*>(tgt + (size_t)col * TD + lane * 4);
    float s = v.x * v.x + v.y * v.y + v.z * v.z + v.w * v.w;
    for (int off = 32; off > 0; off >>= 1) s += __shfl_down(s, off, 64);
    s = __shfl(s, 0, 64);
    const float inv = 1.0f / sqrtf(s);
    ushort4 o;
    o.x = f2bf(v.x * inv); o.y = f2bf(v.y * inv);
    o.z = f2bf(v.z * inv); o.w = f2bf(v.w * inv);
    *reinterpret_cast<ushort4*>(negT + tile_off_us(col, lane)) = o;
}

// ---------------------------------------------------------------------------
// per anchor row: normalized anchor (bf16, tiled), acos*10 numerator, phone.
// ---------------------------------------------------------------------------
__global__ __launch_bounds__(64) void kanchor(const float* __restrict__ ctx,
                                              const float* __restrict__ tgt,
                                              const int* __restrict__ mask_index,
                                              const int* __restrict__ phone,
                                              unsigned short* __restrict__ ancT,
                                              float* __restrict__ acosP,
                                              int* __restrict__ phoneA) {
    const int r = blockIdx.x;
    const int b = r >> 7;
    const int n = r & 127;
    const int t = mask_index[n];
    const int lane = threadIdx.x;
    const size_t base = ((size_t)b * TT + t) * TD;
    float4 a = *reinterpret_cast<const float4*>(ctx + base + lane * 4);
    float4 p = *reinterpret_cast<const float4*>(tgt + base + lane * 4);
    float sa = a.x * a.x + a.y * a.y + a.z * a.z + a.w * a.w;
    float sp = p.x * p.x + p.y * p.y + p.z * p.z + p.w * p.w;
    float dp = a.x * p.x + a.y * p.y + a.z * p.z + a.w * p.w;
    for (int off = 32; off > 0; off >>= 1) {
        sa += __shfl_down(sa, off, 64);
        sp += __shfl_down(sp, off, 64);
        dp += __shfl_down(dp, off, 64);
    }
    sa = __shfl(sa, 0, 64);
    sp = __shfl(sp, 0, 64);
    dp = __shfl(dp, 0, 64);
    const float an = sqrtf(sa);
    const float inva = 1.0f / an;
    if (lane == 0) {
        float cp = dp / (an * sqrtf(sp));
        cp = fminf(1.f, fmaxf(-1.f, cp));
        acosP[r] = acosf(cp) * 10.0f;
        phoneA[r] = phone[b * TT + t];
    }
    ushort4 o;
    o.x = f2bf(a.x * inva); o.y = f2bf(a.y * inva);
    o.z = f2bf(a.z * inva); o.w = f2bf(a.w * inva);
    *reinterpret_cast<ushort4*>(ancT + tile_off_us(r, lane)) = o;
}

// ---------------------------------------------------------------------------
// pass 1: MFMA cos (32 rows x 2048 cols per block), packed LDS histogram,
// flush to global with integer atomics. All operand loads fully coalesced.
// ---------------------------------------------------------------------------
__global__ __launch_bounds__(256, 4) void kpass1(const short8v* __restrict__ negT8,
                                                 const short8v* __restrict__ ancT8,
                                                 const int* __restrict__ phoneT,
                                                 const int* __restrict__ phoneA,
                                                 unsigned* __restrict__ hist) {
    __shared__ unsigned histp[RT][NB / 2 + 1];   // 2 bins packed per u32
    const int tid = threadIdx.x;
    const int w = tid >> 6;
    const int lane = tid & 63;
    const int g = lane >> 4;
    const int c = lane & 15;
    const int rt = blockIdx.x >> 4;
    const int ct = blockIdx.x & 15;
    const int row0 = rt * RT;

    for (int i = tid; i < RT * (NB / 2 + 1); i += 256) (&histp[0][0])[i] = 0u;

    short8v af[2][8];
#pragma unroll
    for (int mt = 0; mt < 2; ++mt)
#pragma unroll
        for (int ks = 0; ks < 8; ++ks)
            af[mt][ks] = ancT8[((rt * 2 + mt) * 8 + ks) * 64 + lane];
    int phA_r[2][4];
#pragma unroll
    for (int mt = 0; mt < 2; ++mt)
#pragma unroll
        for (int j = 0; j < 4; ++j)
            phA_r[mt][j] = phoneA[row0 + mt * 16 + g * 4 + j];
    __syncthreads();

    for (int chunk = 0; chunk < NCHUNK; ++chunk) {
        const int cb = ct * CTILE + w * WCOLS + chunk * 64;
        const int cbblk = cb >> 4;
        float4v acc[2][4];
#pragma unroll
        for (int mt = 0; mt < 2; ++mt)
#pragma unroll
            for (int nt = 0; nt < 4; ++nt)
                acc[mt][nt] = (float4v){0.f, 0.f, 0.f, 0.f};
#pragma unroll
        for (int nt = 0; nt < 4; ++nt) {
            const int b0 = ((cbblk + nt) * 8) * 64 + lane;
#pragma unroll
            for (int ks = 0; ks < 8; ++ks) {
                short8v bf = negT8[b0 + ks * 64];
                acc[0][nt] = __builtin_amdgcn_mfma_f32_16x16x32_bf16(af[0][ks], bf, acc[0][nt], 0, 0, 0);
                acc[1][nt] = __builtin_amdgcn_mfma_f32_16x16x32_bf16(af[1][ks], bf, acc[1][nt], 0, 0, 0);
            }
        }
#pragma unroll
        for (int nt = 0; nt < 4; ++nt) {
            const int ph = phoneT[cb + nt * 16 + c];
#pragma unroll
            for (int mt = 0; mt < 2; ++mt) {
#pragma unroll
                for (int j = 0; j < 4; ++j) {
                    if (ph != phA_r[mt][j]) {
                        float v = fminf(1.f, fmaxf(-1.f, acc[mt][nt][j]));
                        int bb = (int)((v + 1.0f) * 128.0f);
                        bb = bb > NB - 1 ? NB - 1 : bb;
                        atomicAdd(&histp[mt * 16 + g * 4 + j][bb >> 1],
                                  1u << ((bb & 1) * 16));
                    }
                }
            }
        }
    }
    __syncthreads();
    for (int i = tid; i < RT * (NB / 2); i += 256) {
        int r = i >> 7, pb = i & 127;
        unsigned u = histp[r][pb];
        if (u & 0xffffu) atomicAdd(&hist[(size_t)(row0 + r) * NB + pb * 2], u & 0xffffu);
        if (u >> 16)     atomicAdd(&hist[(size_t)(row0 + r) * NB + pb * 2 + 1], u >> 16);
    }
}

// ---------------------------------------------------------------------------
// find the k-th-value bin per row
// ---------------------------------------------------------------------------
__global__ __launch_bounds__(256) void kbstar(const unsigned* __restrict__ hist,
                                              int* __restrict__ bstar,
                                              int* __restrict__ rneedA) {
    const int row = blockIdx.x * 256 + threadIdx.x;
    const unsigned* h = hist + (size_t)row * NB;
    unsigned tot = 0;
    for (int i = 0; i < NB; ++i) tot += h[i];
    int kp = (int)tot < KTOP ? (int)tot : KTOP;
    if (kp == 0) { bstar[row] = -1; rneedA[row] = 0; return; }
    unsigned cum = 0;
    int b = 0;
    for (; b < NB; ++b) {
        if (cum + h[b] >= (unsigned)kp) break;
        cum += h[b];
    }
    bstar[row] = b;
    rneedA[row] = kp - (int)cum;
}

// ---------------------------------------------------------------------------
// pass 2: recompute cos (bit-identical), sum exp(acos*10) for bins < bstar,
// append boundary-bin values to per-row global lists.
// ---------------------------------------------------------------------------
__global__ __launch_bounds__(256, 4) void kpass2(const short8v* __restrict__ negT8,
                                                 const short8v* __restrict__ ancT8,
                                                 const int* __restrict__ phoneT,
                                                 const int* __restrict__ phoneA,
                                                 const int* __restrict__ bstar,
                                                 float* __restrict__ partials,
                                                 float* __restrict__ list,
                                                 int* __restrict__ cnt) {
    __shared__ float rowpart[RT][4];
    const int tid = threadIdx.x;
    const int w = tid >> 6;
    const int lane = tid & 63;
    const int g = lane >> 4;
    const int c = lane & 15;
    const int rt = blockIdx.x >> 4;
    const int ct = blockIdx.x & 15;
    const int row0 = rt * RT;

    short8v af[2][8];
#pragma unroll
    for (int mt = 0; mt < 2; ++mt)
#pragma unroll
        for (int ks = 0; ks < 8; ++ks)
            af[mt][ks] = ancT8[((rt * 2 + mt) * 8 + ks) * 64 + lane];
    int phA_r[2][4], bs_r[2][4];
#pragma unroll
    for (int mt = 0; mt < 2; ++mt)
#pragma unroll
        for (int j = 0; j < 4; ++j) {
            phA_r[mt][j] = phoneA[row0 + mt * 16 + g * 4 + j];
            bs_r[mt][j] = bstar[row0 + mt * 16 + g * 4 + j];
        }

    float lsum[2][4];
#pragma unroll
    for (int mt = 0; mt < 2; ++mt)
#pragma unroll
        for (int j = 0; j < 4; ++j) lsum[mt][j] = 0.f;

    for (int chunk = 0; chunk < NCHUNK; ++chunk) {
        const int cb = ct * CTILE + w * WCOLS + chunk * 64;
        const int cbblk = cb >> 4;
        float4v acc[2][4];
#pragma unroll
        for (int mt = 0; mt < 2; ++mt)
#pragma unroll
            for (int nt = 0; nt < 4; ++nt)
                acc[mt][nt] = (float4v){0.f, 0.f, 0.f, 0.f};
#pragma unroll
        for (int nt = 0; nt < 4; ++nt) {
            const int b0 = ((cbblk + nt) * 8) * 64 + lane;
#pragma unroll
            for (int ks = 0; ks < 8; ++ks) {
                short8v bf = negT8[b0 + ks * 64];
                acc[0][nt] = __builtin_amdgcn_mfma_f32_16x16x32_bf16(af[0][ks], bf, acc[0][nt], 0, 0, 0);
                acc[1][nt] = __builtin_amdgcn_mfma_f32_16x16x32_bf16(af[1][ks], bf, acc[1][nt], 0, 0, 0);
            }
        }
#pragma unroll
        for (int nt = 0; nt < 4; ++nt) {
            const int ph = phoneT[cb + nt * 16 + c];
#pragma unroll
            for (int mt = 0; mt < 2; ++mt) {
#pragma unroll
                for (int j = 0; j < 4; ++j) {
                    if (ph != phA_r[mt][j]) {
                        float v = fminf(1.f, fmaxf(-1.f, acc[mt][nt][j]));
                        int bb = (int)((v + 1.0f) * 128.0f);
                        bb = bb > NB - 1 ? NB - 1 : bb;
                        const int bs = bs_r[mt][j];
                        if (bb < bs) {
                            lsum[mt][j] += expf(acosf(v) * 10.0f);
                        } else if (bb == bs) {
                            const int rl = row0 + mt * 16 + g * 4 + j;
                            int idx = atomicAdd(&cnt[rl], 1);
                            if (idx < CAP) list[(size_t)rl * CAP + idx] = v;
                        }
                    }
                }
            }
        }
    }
#pragma unroll
    for (int mt = 0; mt < 2; ++mt) {
#pragma unroll
        for (int j = 0; j < 4; ++j) {
            float s = lsum[mt][j];
            s += __shfl_xor(s, 1, 64);
            s += __shfl_xor(s, 2, 64);
            s += __shfl_xor(s, 4, 64);
            s += __shfl_xor(s, 8, 64);
            if (c == 0) rowpart[mt * 16 + g * 4 + j][w] = s;
        }
    }
    __syncthreads();
    if (tid < RT) {
        float s = (rowpart[tid][0] + rowpart[tid][1]) + (rowpart[tid][2] + rowpart[tid][3]);
        partials[(size_t)(row0 + tid) * CTN + ct] = s;
    }
}

// ---------------------------------------------------------------------------
// final per-row: sum partials (fixed order) + exact remainder extraction.
// ---------------------------------------------------------------------------
__global__ __launch_bounds__(64) void kfinal(const float* __restrict__ partials,
                                             const float* __restrict__ list,
                                             const int* __restrict__ cnt,
                                             const int* __restrict__ rneedA,
                                             const float* __restrict__ acosP,
                                             float* __restrict__ logits) {
    __shared__ float sl[CAP];
    const int row = blockIdx.x;
    const int lane = threadIdx.x;
    int lc = cnt[row];
    if (lc > CAP) lc = CAP;
    int rn = rneedA[row];
    if (rn > lc) rn = lc;

    float den = 0.f;
    for (int t = 0; t < CTN; ++t) den += partials[(size_t)row * CTN + t];

    for (int i = lane; i < lc; i += 64) sl[i] = list[(size_t)row * CAP + i];
    __syncthreads();

    for (int it = 0; it < rn; ++it) {
        float mv = 1e30f;
        int mi = -1;
        for (int i = lane; i < lc; i += 64) {
            float x = sl[i];
            if (x < mv) { mv = x; mi = i; }
        }
#pragma unroll
        for (int off = 1; off < 64; off <<= 1) {
            float ov = __shfl_xor(mv, off, 64);
            int oi = __shfl_xor(mi, off, 64);
            if (ov < mv || (ov == mv && oi >= 0 && (mi < 0 || oi < mi))) { mv = ov; mi = oi; }
        }
        den += expf(acosf(fminf(1.f, fmaxf(-1.f, mv))) * 10.0f);
        if (lane == 0 && mi >= 0) sl[mi] = 1e30f;
        __syncthreads();
    }
    if (lane == 0) logits[row] = acosP[row] - logf(den);
}

__global__ __launch_bounds__(256) void kloss(const float* __restrict__ logits,
                                             float* __restrict__ out) {
    __shared__ float red[256];
    int tid = threadIdx.x;
    float s = 0.f;
    for (int i = tid; i < BN; i += 256) s += logits[i];
    red[tid] = s;
    __syncthreads();
    for (int st = 128; st > 0; st >>= 1) {
        if (tid < st) red[tid] += red[tid + st];
        __syncthreads();
    }
    if (tid == 0) out[0] = -red[0] / (float)BN;
}

extern "C" void kernel_launch(void* const* d_in, const int* in_sizes, int n_in,
                              void* d_out, int out_size, void* d_ws, size_t ws_size,
                              hipStream_t stream) {
    (void)in_sizes; (void)n_in; (void)out_size; (void)ws_size;
    const float* ctx   = (const float*)d_in[0];
    const float* tgt   = (const float*)d_in[1];
    const int*   mask  = (const int*)d_in[2];
    const int*   phone = (const int*)d_in[3];
    float* out = (float*)d_out;

    char* p = (char*)d_ws;
    unsigned short* negT = (unsigned short*)p;            p += (size_t)BT * TD * 2;  // 16 MB
    unsigned short* ancT = (unsigned short*)p;            p += (size_t)BN * TD * 2;  // 1 MB
    float* acosP  = (float*)p;                            p += (size_t)BN * 4;
    int*   phoneA = (int*)p;                              p += (size_t)BN * 4;
    unsigned* hist = (unsigned*)p;                        p += (size_t)BN * NB * 4;  // 2 MB
    int*   bstarA = (int*)p;                              p += (size_t)BN * 4;
    int*   rneedA = (int*)p;                              p += (size_t)BN * 4;
    int*   cntA   = (int*)p;                              p += (size_t)BN * 4;
    float* partials = (float*)p;                          p += (size_t)BN * CTN * 4;
    float* listA  = (float*)p;                            p += (size_t)BN * CAP * 4; // 4 MB
    float* logits = (float*)p;                            p += (size_t)BN * 4;

    kzero<<<(BN * NB) / 256, 256, 0, stream>>>(hist, cntA);
    kprep<<<BT / 4, 256, 0, stream>>>(tgt, negT);
    kanchor<<<BN, 64, 0, stream>>>(ctx, tgt, mask, phone, ancT, acosP, phoneA);
    kpass1<<<64 * CTN, 256, 0, stream>>>((const short8v*)negT, (const short8v*)ancT,
                                         phone, phoneA, hist);
    kbstar<<<BN / 256, 256, 0, stream>>>(hist, bstarA, rneedA);
    kpass2<<<64 * CTN, 256, 0, stream>>>((const short8v*)negT, (const short8v*)ancT,
                                         phone, phoneA, bstarA, partials, listA, cntA);
    kfinal<<<BN, 64, 0, stream>>>(partials, listA, cntA, rneedA, acosP, logits);
    kloss<<<1, 256, 0, stream>>>(logits, out);
}